// Round 10
// baseline (348.056 us; speedup 1.0000x reference)
//
#include <hip/hip_runtime.h>
#include <math.h>

#define NB 512
#define NN 256
#define NCACHE 61
#define LAP_INF 1e30f

// ws layout (mode 2): flag@0, nk@1024 (mode-1 only), rmk(u64)@8192 (1MB),
//                     Pt@8192+1M
#define WS_NK_OFF 1024
#define WS_RMK_OFF 8192
#define WS_PT_OFF_FULL (8192 + 1024 * 1024)
#define WS_PT_OFF_R4 8192

// ---------------------------------------------------------------------------
// pad_mask layout detection: flag = 1 (int32), 2 (float32), 0 (bytes/bool8).
// ---------------------------------------------------------------------------
__global__ __launch_bounds__(1024)
void detect_kernel(const unsigned int* __restrict__ pw, int* __restrict__ flag) {
  __shared__ int notInt, notFloat;
  if (threadIdx.x == 0) { notInt = 0; notFloat = 0; }
  __syncthreads();
  int li = 0, lf = 0;
  for (int t = threadIdx.x; t < 32768; t += 1024) {
    unsigned int w = pw[t];
    if (w > 1u) li = 1;
    if (w != 0u && w != 0x3F800000u) lf = 1;
  }
  if (li) atomicOr(&notInt, 1);
  if (lf) atomicOr(&notFloat, 1);
  __syncthreads();
  if (threadIdx.x == 0) flag[0] = (!notInt) ? 1 : ((!notFloat) ? 2 : 0);
}

// ---------------------------------------------------------------------------
// n_k[k] (mode-1 fallback only; mode 2 computes inline in each kernel).
// ---------------------------------------------------------------------------
__global__ __launch_bounds__(64)
void nk_kernel(const void* __restrict__ pm, const int* __restrict__ flag,
               int* __restrict__ nk) {
  const int k = blockIdx.x;
  const int lane = threadIdx.x;
  const int fl = flag[0];
  int cnt4 = 0;
  if (fl == 1) {
    const int* p = ((const int*)pm) + k * NN;
#pragma unroll
    for (int q = 0; q < 4; ++q) cnt4 += (p[lane * 4 + q] != 0);
  } else if (fl == 2) {
    const float* p = ((const float*)pm) + k * NN;
#pragma unroll
    for (int q = 0; q < 4; ++q) cnt4 += (p[lane * 4 + q] != 0.0f);
  } else {
    const unsigned char* p = ((const unsigned char*)pm) + k * NN;
#pragma unroll
    for (int q = 0; q < 4; ++q) cnt4 += (p[lane * 4 + q] != 0);
  }
#pragma unroll
  for (int off = 32; off > 0; off >>= 1) cnt4 += __shfl_down(cnt4, off);
  if (lane == 0) nk[k] = cnt4;
}

__device__ __forceinline__ unsigned f2o(float f) {
  unsigned x = __float_as_uint(f);
  return x ^ ((unsigned)((int)x >> 31) | 0x80000000u);
}
__device__ __forceinline__ float o2f(unsigned m) {
  unsigned x = (m & 0x80000000u) ? (m & 0x7FFFFFFFu) : ~m;
  return __uint_as_float(x);
}

// ---------------------------------------------------------------------------
// FUSED transpose + row-min (mode 2), R10: inline n_k + double-buffered tile
// (1 barrier/iter instead of 2). Row-min as packed u64 key (f2o(v)<<32 | j):
// min == lowest value, ties -> lowest j, byte-identical to serial first-index.
// ---------------------------------------------------------------------------
__global__ __launch_bounds__(256)
void transpose_rowmin_kernel(const float* __restrict__ in,
                             float* __restrict__ out,
                             const void* __restrict__ pm,
                             const int* __restrict__ flag,
                             unsigned long long* __restrict__ rmk) {
  const int k = blockIdx.z;
  const int i0 = blockIdx.x * 32;
  const int tx = threadIdx.x, ty = threadIdx.y;
  const int tid = ty * 32 + tx;

  // ---- inline n_k (1KB read + ballot reduce; replaces nk_kernel) ----
  __shared__ int nkL;
  if (tid == 0) nkL = 0;
  __syncthreads();
  {
    const int fl = flag[0];
    int pred;
    if (fl == 1)      pred = (((const int*)pm)[k * NN + tid] != 0);
    else if (fl == 2) pred = (((const float*)pm)[k * NN + tid] != 0.0f);
    else              pred = (((const unsigned char*)pm)[k * NN + tid] != 0);
    const unsigned long long bal = __ballot(pred);
    if ((tid & 63) == 0) atomicAdd(&nkL, __popcll(bal));
  }
  __syncthreads();
  int bnd = nkL;
  bnd = bnd > NCACHE ? bnd : NCACHE;
  if (i0 >= bnd) return;

  __shared__ float tile[2][32][33];
  __shared__ unsigned long long keyL[8][32];
  const float* A = in + ((size_t)k << 16);
  float* Bp = out + ((size_t)k << 16);

  // preload j0 = 0 into buf 0
#pragma unroll
  for (int r = 0; r < 32; r += 8) {
    float x = A[(size_t)(ty + r) * NN + (i0 + tx)];
    tile[0][ty + r][tx] = isfinite(x) ? x : 1e6f;
  }
  __syncthreads();

  unsigned long long best = ~0ull;
  int buf = 0;
#pragma unroll 1
  for (int j0 = 0; j0 < NN; j0 += 32) {
    // store + row-min accumulate from tile[buf]
#pragma unroll
    for (int r = 0; r < 32; r += 8) {
      Bp[(size_t)(i0 + ty + r) * NN + (j0 + tx)] = tile[buf][tx][ty + r];
      const float v = tile[buf][ty + r][tx];  // Pt[i0+tx][j0+ty+r]
      const unsigned long long key =
          ((unsigned long long)f2o(v) << 32) | (unsigned)(j0 + ty + r);
      if (key < best) best = key;
    }
    // prefetch next column-tile into the other buffer
    if (j0 + 32 < NN) {
#pragma unroll
      for (int r = 0; r < 32; r += 8) {
        float x = A[(size_t)(j0 + 32 + ty + r) * NN + (i0 + tx)];
        tile[buf ^ 1][ty + r][tx] = isfinite(x) ? x : 1e6f;
      }
    }
    __syncthreads();  // single barrier: buf stores done, buf^1 loads done
    buf ^= 1;
  }

  keyL[ty][tx] = best;
  __syncthreads();
  if (ty == 0) {
    unsigned long long b = keyL[0][tx];
#pragma unroll
    for (int s = 1; s < 8; ++s) {
      const unsigned long long c = keyL[s][tx];
      if (c < b) b = c;
    }
    rmk[k * NN + i0 + tx] = b;
  }
}

// ---------------------------------------------------------------------------
// Legacy transpose (modes 0/1 fallback; no rmk side-channel).
// ---------------------------------------------------------------------------
__global__ __launch_bounds__(256)
void transpose_kernel(const float* __restrict__ in, float* __restrict__ out,
                      const int* __restrict__ nk) {
  const int k = blockIdx.z;
  const int i0 = blockIdx.x * 32;
  int bnd = nk[k];
  bnd = bnd > NCACHE ? bnd : NCACHE;
  if (i0 >= bnd) return;
  __shared__ float tile[32][33];
  const float* A = in + ((size_t)k << 16);
  float* Bp = out + ((size_t)k << 16);
  const int tx = threadIdx.x, ty = threadIdx.y;
  const int j0 = blockIdx.y * 32;
#pragma unroll
  for (int r = 0; r < 32; r += 8) {
    float x = A[(size_t)(j0 + ty + r) * NN + (i0 + tx)];
    tile[ty + r][tx] = isfinite(x) ? x : 1e6f;
  }
  __syncthreads();
#pragma unroll
  for (int r = 0; r < 32; r += 8) {
    Bp[(size_t)(i0 + ty + r) * NN + (j0 + tx)] = tile[tx][ty + r];
  }
}

// ---------------------------------------------------------------------------
// DPP wave64 u32 min (VALU-rate).
// ---------------------------------------------------------------------------
template <int CTRL>
__device__ __forceinline__ unsigned dpp_min_step(unsigned x) {
  unsigned y = (unsigned)__builtin_amdgcn_update_dpp((int)x, (int)x, CTRL, 0xF, 0xF, false);
  return y < x ? y : x;
}
__device__ __forceinline__ unsigned wave_min_u32(unsigned x) {
  x = dpp_min_step<0xB1>(x);   // quad_perm [1,0,3,2]
  x = dpp_min_step<0x4E>(x);   // quad_perm [2,3,0,1]
  x = dpp_min_step<0x141>(x);  // row_half_mirror
  x = dpp_min_step<0x140>(x);  // row_mirror
  x = dpp_min_step<0x142>(x);  // row_bcast15
  x = dpp_min_step<0x143>(x);  // row_bcast31
  return (unsigned)__builtin_amdgcn_readlane((int)x, 63);
}
__device__ __forceinline__ int sel4(const int a[4], int s) {
  return (s == 0) ? a[0] : (s == 1) ? a[1] : (s == 2) ? a[2] : a[3];
}
__device__ __forceinline__ void set4(int a[4], int s, int v) {
  if (s == 0) a[0] = v; else if (s == 1) a[1] = v;
  else if (s == 2) a[2] = v; else a[3] = v;
}
__device__ __forceinline__ void setf4(float a[4], int s, float v) {
  if (s == 0) a[0] = v; else if (s == 1) a[1] = v;
  else if (s == 2) a[2] = v; else a[3] = v;
}

// ---------------------------------------------------------------------------
// One wave64 per batch. Lane L owns cols 4L..4L+3 (v, shortest, pathrow, SC,
// row4col) and rows 4L..4L+3 (u, SR, col4row) in registers.
// mode 2: greedy init from packed rmk (u64 min|arg); parallel conflict
//         resolution (LDS atomicMin == serial first-come-lowest-row).
// mode 1: R4-style in-lap greedy scan.  mode 0: strided direct.
// Phase 2: JV shortest augmenting path, exact reference float op order,
//          barrier-free (sh gathered via shuffles, not LDS) — R7: -41us.
// n_k computed inline for all modes (R10; nk_kernel dropped from mode 2).
// NOTE (R2): v must stay 0 in phase-1 duals (bit-exact slack requirement).
// NOTE (R5): NCACHE=61; 77 regressed. Fill is 8-deep pipelined (R6).
// ---------------------------------------------------------------------------
__global__ __launch_bounds__(64)
void lap_kernel(const float* __restrict__ costs, const void* __restrict__ pm,
                const int* __restrict__ flag,
                const unsigned long long* __restrict__ rmk,
                const float* __restrict__ Pt, int* __restrict__ out, int mode) {
  const int k = blockIdx.x;
  const int lane = threadIdx.x;

  __shared__ __align__(16) float rowCache[NCACHE][NN];
  __shared__ int freeRowsL[NN];
  __shared__ int winnerL[NN];

  const float* PtK = Pt + ((size_t)k << 16);
  const float* costK = costs + ((size_t)k << 16);

  int n_k;
  {
    const int fl = flag[0];
    int cnt4 = 0;
    if (fl == 1) {
      const int* p = ((const int*)pm) + k * NN;
#pragma unroll
      for (int q = 0; q < 4; ++q) cnt4 += (p[lane * 4 + q] != 0);
    } else if (fl == 2) {
      const float* p = ((const float*)pm) + k * NN;
#pragma unroll
      for (int q = 0; q < 4; ++q) cnt4 += (p[lane * 4 + q] != 0.0f);
    } else {
      const unsigned char* p = ((const unsigned char*)pm) + k * NN;
#pragma unroll
      for (int q = 0; q < 4; ++q) cnt4 += (p[lane * 4 + q] != 0);
    }
#pragma unroll
    for (int off = 32; off > 0; off >>= 1) cnt4 += __shfl_down(cnt4, off);
    n_k = __shfl(cnt4, 0);
  }

  float vv[4] = {0.f, 0.f, 0.f, 0.f};
  float uu[4] = {0.f, 0.f, 0.f, 0.f};
  int r4c[4] = {-1, -1, -1, -1};   // row4col, col-indexed
  int c4r[4] = {-1, -1, -1, -1};   // col4row, row-indexed
  int ja[4] = {-1, -1, -1, -1};    // greedy argmin per owned row
  int nfree = 0;                    // wave-uniform

  if (mode == 2) {
    // ---- fill LDS row cache, 8-deep software pipeline (R5 post-mortem) ----
#pragma unroll 1
    for (int base = 0; base + 8 <= NCACHE; base += 8) {
      float4 b[8];
#pragma unroll
      for (int r = 0; r < 8; ++r)
        b[r] = *(const float4*)(PtK + (size_t)(base + r) * NN + lane * 4);
#pragma unroll
      for (int r = 0; r < 8; ++r)
        *(float4*)(&rowCache[base + r][lane * 4]) = b[r];
    }
    {
      const int base = (NCACHE / 8) * 8;
      float4 b[NCACHE - (NCACHE / 8) * 8];
#pragma unroll
      for (int r = 0; r < NCACHE - (NCACHE / 8) * 8; ++r)
        b[r] = *(const float4*)(PtK + (size_t)(base + r) * NN + lane * 4);
#pragma unroll
      for (int r = 0; r < NCACHE - (NCACHE / 8) * 8; ++r)
        *(float4*)(&rowCache[base + r][lane * 4]) = b[r];
    }

    // ---- phase 1: greedy init from packed row minima ----
    const unsigned long long* rk = rmk + k * NN + lane * 4;
    unsigned long long kk[4];
#pragma unroll
    for (int q = 0; q < 4; ++q) kk[q] = rk[q];
#pragma unroll
    for (int q = 0; q < 4; ++q) {
      uu[q] = o2f((unsigned)(kk[q] >> 32));
      ja[q] = (int)(unsigned)(kk[q] & 0xFFFFFFFFu);
      if (lane * 4 + q >= n_k) uu[q] = 0.f;
    }

    // parallel conflict resolution: column winner = lowest claiming row
    // (identical to serial first-come walk in ascending row order).
    for (int t = lane; t < NN; t += 64) winnerL[t] = 0x7FFFFFFF;
    __syncthreads();
#pragma unroll
    for (int q = 0; q < 4; ++q) {
      const int row = lane * 4 + q;
      if (row < n_k) atomicMin(&winnerL[ja[q]], row);
    }
    __syncthreads();
#pragma unroll
    for (int s = 0; s < 4; ++s) {
      const int w = winnerL[lane * 4 + s];
      r4c[s] = (w == 0x7FFFFFFF) ? -1 : w;
    }
    unsigned fm = 0;
#pragma unroll
    for (int q = 0; q < 4; ++q) {
      const int row = lane * 4 + q;
      const bool valid = row < n_k;
      const bool won = valid && (winnerL[ja[q]] == row);
      c4r[q] = won ? ja[q] : -1;
      if (valid && !won) fm |= (1u << q);
    }
    // compact free rows ascending (row = 4*lane+q, lane-major == ascending)
    const int cnt = __popc(fm);
    int x = cnt;
#pragma unroll
    for (int off = 1; off < 64; off <<= 1) {
      const int y = __shfl_up(x, off);
      if (lane >= off) x += y;
    }
    nfree = __shfl(x, 63);
    int pos = x - cnt;
#pragma unroll
    for (int q = 0; q < 4; ++q) {
      if ((fm >> q) & 1u) { freeRowsL[pos] = lane * 4 + q; ++pos; }
    }
    __syncthreads();  // fill ds_writes + freeRowsL visible before phase 2
  } else {
    // ---- legacy fill (mode 1 / mode 0) ----
    if (mode >= 1) {
      const float4* s4 = (const float4*)PtK;
      float4* c4 = (float4*)rowCache;
      for (int t = lane; t < NCACHE * (NN / 4); t += 64) c4[t] = s4[t];
    } else {
      for (int e = lane; e < NCACHE * NN; e += 64) {
        const int i = e >> 8, j = e & 255;
        float x = costK[(size_t)j * NN + i];
        rowCache[i][j] = isfinite(x) ? x : 1e6f;
      }
    }
    __syncthreads();
    // ---- in-lap greedy scan (R4 behavior) ----
    float4 carry = {0.f, 0.f, 0.f, 0.f};
    for (int r = 0; r < n_k; ++r) {
      float cc[4];
      if (r < NCACHE) {
        const float4 rv = *(const float4*)(&rowCache[r][lane * 4]);
        cc[0] = rv.x; cc[1] = rv.y; cc[2] = rv.z; cc[3] = rv.w;
      } else if (mode >= 1) {
        cc[0] = carry.x; cc[1] = carry.y; cc[2] = carry.z; cc[3] = carry.w;
      } else {
#pragma unroll
        for (int q = 0; q < 4; ++q) {
          float x = costK[(size_t)(lane * 4 + q) * NN + r];
          cc[q] = isfinite(x) ? x : 1e6f;
        }
      }
      if (mode >= 1 && r + 1 >= NCACHE && r + 1 < n_k)
        carry = *(const float4*)(PtK + (size_t)(r + 1) * NN + lane * 4);

      unsigned lbv = 0xFFFFFFFFu;
      int lbq = 0;
#pragma unroll
      for (int q = 0; q < 4; ++q) {
        const unsigned m = f2o(cc[q]);
        if (m < lbv) { lbv = m; lbq = q; }
      }
      const unsigned gv = wave_min_u32(lbv);
      const unsigned long long cmask = __ballot(lbv == gv);
      const int owner = __ffsll((unsigned long long)cmask) - 1;
      const int js = (owner << 2) + __builtin_amdgcn_readlane(lbq, owner);
      if (lane == (r >> 2)) setf4(uu, r & 3, o2f(gv));
      const int occ = __builtin_amdgcn_readlane(sel4(r4c, js & 3), owner);
      if (occ < 0) {
        if (lane == owner) set4(r4c, js & 3, r);
        if (lane == (r >> 2)) set4(c4r, r & 3, js);
      } else {
        if (lane == 0) freeRowsL[nfree] = r;
        nfree++;
      }
    }
    __syncthreads();  // freeRowsL visible
  }

  // ---- phase 2: shortest augmenting path (barrier-free, registers+shfl) ----
  for (int t = 0; t < nfree; ++t) {
    const int cur = freeRowsL[t];
    float sh[4] = {LAP_INF, LAP_INF, LAP_INF, LAP_INF};
    int pr[4] = {-1, -1, -1, -1};
    unsigned scm = 0;  // SC bits, this lane's 4 cols
    unsigned srm = 0;  // SR bits, this lane's 4 rows
    float minval = 0.f;
    int i = cur, sink = -1;

    while (sink < 0) {
      const int islot = i & 3, iowner = i >> 2;
      if (lane == iowner) srm |= (1u << islot);
      const float su = (islot == 0) ? uu[0] : (islot == 1) ? uu[1]
                     : (islot == 2) ? uu[2] : uu[3];
      const float ui = __int_as_float(
          __builtin_amdgcn_readlane(__float_as_int(su), iowner));

      float cc[4];
      if (i < NCACHE) {
        const float4 rv = *(const float4*)(&rowCache[i][lane * 4]);
        cc[0] = rv.x; cc[1] = rv.y; cc[2] = rv.z; cc[3] = rv.w;
      } else if (mode >= 1) {
        const float4 rv = *(const float4*)(PtK + (size_t)i * NN + lane * 4);
        cc[0] = rv.x; cc[1] = rv.y; cc[2] = rv.z; cc[3] = rv.w;
      } else {
#pragma unroll
        for (int q = 0; q < 4; ++q) {
          float x = costK[(size_t)(lane * 4 + q) * NN + i];
          cc[q] = isfinite(x) ? x : 1e6f;
        }
      }

      unsigned mq[4];
#pragma unroll
      for (int q = 0; q < 4; ++q) {
        // exact reference order: ((minval + cost) - u[i]) - v[j]
        float r = minval + cc[q];
        r = r - ui;
        r = r - vv[q];
        const bool sc = (scm >> q) & 1u;
        if (!sc && r < sh[q]) { sh[q] = r; pr[q] = i; }
        mq[q] = sc ? 0xFFFFFFFFu : f2o(sh[q]);
      }
      // tree-structured lane-local argmin; strict < keeps first index.
      unsigned ma = mq[0]; int qa = 0;
      if (mq[1] < ma) { ma = mq[1]; qa = 1; }
      unsigned mc = mq[2]; int qc = 2;
      if (mq[3] < mc) { mc = mq[3]; qc = 3; }
      unsigned lbv = ma; int lbq = qa;
      if (mc < ma) { lbv = mc; lbq = qc; }

      // Pack (candidate next-row, q) pre-reduce; one readlane post-reduce.
      const int cand = sel4(r4c, lbq);
      const unsigned pack = (unsigned)lbq | ((unsigned)(cand + 1) << 2);

      const unsigned gv = wave_min_u32(lbv);
      minval = o2f(gv);
      const unsigned long long cmask = __ballot(lbv == gv);
      const int owner = __ffsll((unsigned long long)cmask) - 1;
      const unsigned pk = (unsigned)__builtin_amdgcn_readlane((int)pack, owner);
      const int js = (owner << 2) + (int)(pk & 3u);
      if (lane == owner) scm |= (1u << lbq);
      const int nxt = (int)(pk >> 2) - 1;
      if (nxt < 0) sink = js; else i = nxt;
    }

    // ---- dual updates (Crouse 2016): gather shortest[c4r[q]] via shfl ----
    float gv4[4];
#pragma unroll
    for (int q = 0; q < 4; ++q) {
      const int tgt = c4r[q] >= 0 ? c4r[q] : 0;  // clamp; unused when invalid
      const int srcLane = tgt >> 2, slot = tgt & 3;
      const float g0 = __shfl(sh[0], srcLane);
      const float g1 = __shfl(sh[1], srcLane);
      const float g2 = __shfl(sh[2], srcLane);
      const float g3 = __shfl(sh[3], srcLane);
      gv4[q] = (slot == 0) ? g0 : (slot == 1) ? g1 : (slot == 2) ? g2 : g3;
    }
#pragma unroll
    for (int q = 0; q < 4; ++q) {
      if ((srm >> q) & 1u) {
        const int row = lane * 4 + q;
        if (row == cur) uu[q] = uu[q] + minval;
        else uu[q] = uu[q] + (minval - gv4[q]);
      }
      if ((scm >> q) & 1u) vv[q] = vv[q] - (minval - sh[q]);
    }

    // ---- augment along alternating path: pure registers ----
    int j = sink;
    bool done = false;
    while (!done) {
      const int pi = __builtin_amdgcn_readlane(sel4(pr, j & 3), j >> 2);
      if (lane == (j >> 2)) set4(r4c, j & 3, pi);
      const int jn = __builtin_amdgcn_readlane(sel4(c4r, pi & 3), pi >> 2);
      if (lane == (pi >> 2)) set4(c4r, pi & 3, j);
      done = (pi == cur);
      j = jn;
    }
  }

  // ---- output: valid rows get col4row; padded rows get unused cols asc ----
  int* outK = out + k * NN;
#pragma unroll
  for (int q = 0; q < 4; ++q) {
    const int row = lane * 4 + q;
    if (row < n_k) outK[row] = c4r[q];
  }
  // column j unused <=> r4c[j&3] < 0 on lane j>>2 (only rows < n_k match).
  unsigned um = 0;
#pragma unroll
  for (int s = 0; s < 4; ++s)
    if (r4c[s] < 0) um |= (1u << s);
  const int uc = __popc(um);
  int ux = uc;
#pragma unroll
  for (int off = 1; off < 64; off <<= 1) {
    const int uy = __shfl_up(ux, off);
    if (lane >= off) ux += uy;
  }
  int upos = ux - uc;
#pragma unroll
  for (int s = 0; s < 4; ++s) {
    if ((um >> s) & 1u) { outK[n_k + upos] = lane * 4 + s; ++upos; }
  }
}

extern "C" void kernel_launch(void* const* d_in, const int* in_sizes, int n_in,
                              void* d_out, int out_size, void* d_ws, size_t ws_size,
                              hipStream_t stream) {
  const float* costs = (const float*)d_in[0];
  const void* pm = d_in[1];
  int* out = (int*)d_out;

  int* flag = (int*)d_ws;
  int* nk = (int*)((char*)d_ws + WS_NK_OFF);
  const size_t ptBytes = (size_t)NB * NN * NN * sizeof(float);

  int mode;
  unsigned long long* rmk; float* Pt;
  if (ws_size >= WS_PT_OFF_FULL + ptBytes) {
    mode = 2;
    rmk = (unsigned long long*)((char*)d_ws + WS_RMK_OFF);
    Pt = (float*)((char*)d_ws + WS_PT_OFF_FULL);
  } else if (ws_size >= WS_PT_OFF_R4 + ptBytes) {
    mode = 1;
    rmk = (unsigned long long*)d_ws;
    Pt = (float*)((char*)d_ws + WS_PT_OFF_R4);
  } else {
    mode = 0;
    rmk = (unsigned long long*)d_ws;
    Pt = (float*)costs;  // unused
  }

  detect_kernel<<<1, 1024, 0, stream>>>((const unsigned int*)pm, flag);
  if (mode == 2) {
    dim3 g(8, 1, NB), b(32, 8);
    transpose_rowmin_kernel<<<g, b, 0, stream>>>(costs, Pt, pm, flag, rmk);
  } else if (mode == 1) {
    nk_kernel<<<NB, 64, 0, stream>>>(pm, flag, nk);
    dim3 g(8, 8, NB), b(32, 8);
    transpose_kernel<<<g, b, 0, stream>>>(costs, Pt, nk);
  }
  lap_kernel<<<NB, 64, 0, stream>>>(costs, pm, flag, rmk, Pt, out, mode);
}

// Round 11
// 344.911 us; speedup vs baseline: 1.0091x; 1.0091x over previous
//
#include <hip/hip_runtime.h>
#include <math.h>

#define NB 512
#define NN 256
#define NCACHE 61
#define LAP_INF 1e30f

// ws layout (mode 2): flag@0, nk@1024, rmk(u64)@8192 (1MB), Pt@8192+1M
#define WS_NK_OFF 1024
#define WS_RMK_OFF 8192
#define WS_PT_OFF_FULL (8192 + 1024 * 1024)
#define WS_PT_OFF_R4 8192

// ---------------------------------------------------------------------------
// pad_mask layout detection: flag = 1 (int32), 2 (float32), 0 (bytes/bool8).
// ---------------------------------------------------------------------------
__global__ __launch_bounds__(1024)
void detect_kernel(const unsigned int* __restrict__ pw, int* __restrict__ flag) {
  __shared__ int notInt, notFloat;
  if (threadIdx.x == 0) { notInt = 0; notFloat = 0; }
  __syncthreads();
  int li = 0, lf = 0;
  for (int t = threadIdx.x; t < 32768; t += 1024) {
    unsigned int w = pw[t];
    if (w > 1u) li = 1;
    if (w != 0u && w != 0x3F800000u) lf = 1;
  }
  if (li) atomicOr(&notInt, 1);
  if (lf) atomicOr(&notFloat, 1);
  __syncthreads();
  if (threadIdx.x == 0) flag[0] = (!notInt) ? 1 : ((!notFloat) ? 2 : 0);
}

// ---------------------------------------------------------------------------
// n_k[k] (mode-1 fallback only; mode 2 gets nk from transpose_rowmin).
// ---------------------------------------------------------------------------
__global__ __launch_bounds__(64)
void nk_kernel(const void* __restrict__ pm, const int* __restrict__ flag,
               int* __restrict__ nk) {
  const int k = blockIdx.x;
  const int lane = threadIdx.x;
  const int fl = flag[0];
  int cnt4 = 0;
  if (fl == 1) {
    const int* p = ((const int*)pm) + k * NN;
#pragma unroll
    for (int q = 0; q < 4; ++q) cnt4 += (p[lane * 4 + q] != 0);
  } else if (fl == 2) {
    const float* p = ((const float*)pm) + k * NN;
#pragma unroll
    for (int q = 0; q < 4; ++q) cnt4 += (p[lane * 4 + q] != 0.0f);
  } else {
    const unsigned char* p = ((const unsigned char*)pm) + k * NN;
#pragma unroll
    for (int q = 0; q < 4; ++q) cnt4 += (p[lane * 4 + q] != 0);
  }
#pragma unroll
  for (int off = 32; off > 0; off >>= 1) cnt4 += __shfl_down(cnt4, off);
  if (lane == 0) nk[k] = cnt4;
}

__device__ __forceinline__ unsigned f2o(float f) {
  unsigned x = __float_as_uint(f);
  return x ^ ((unsigned)((int)x >> 31) | 0x80000000u);
}
__device__ __forceinline__ float o2f(unsigned m) {
  unsigned x = (m & 0x80000000u) ? (m & 0x7FFFFFFFu) : ~m;
  return __uint_as_float(x);
}

// ---------------------------------------------------------------------------
// FUSED transpose + row-min (mode 2): inline n_k (also PUBLISHED to nk[] for
// lap — R10 post-mortem: lap reading nk[k] is ~3us faster than recomputing),
// double-buffered tile (1 barrier/iter). Row-min as packed u64 key
// (f2o(v)<<32 | j): min == lowest value, ties -> lowest j, byte-identical
// to the serial first-index scan.
// ---------------------------------------------------------------------------
__global__ __launch_bounds__(256)
void transpose_rowmin_kernel(const float* __restrict__ in,
                             float* __restrict__ out,
                             const void* __restrict__ pm,
                             const int* __restrict__ flag,
                             int* __restrict__ nk,
                             unsigned long long* __restrict__ rmk) {
  const int k = blockIdx.z;
  const int i0 = blockIdx.x * 32;
  const int tx = threadIdx.x, ty = threadIdx.y;
  const int tid = ty * 32 + tx;

  // ---- inline n_k (1KB read + ballot reduce) ----
  __shared__ int nkL;
  if (tid == 0) nkL = 0;
  __syncthreads();
  {
    const int fl = flag[0];
    int pred;
    if (fl == 1)      pred = (((const int*)pm)[k * NN + tid] != 0);
    else if (fl == 2) pred = (((const float*)pm)[k * NN + tid] != 0.0f);
    else              pred = (((const unsigned char*)pm)[k * NN + tid] != 0);
    const unsigned long long bal = __ballot(pred);
    if ((tid & 63) == 0) atomicAdd(&nkL, __popcll(bal));
  }
  __syncthreads();
  // publish n_k for lap_kernel (one writer per batch)
  if (blockIdx.x == 0 && tid == 0) nk[k] = nkL;
  int bnd = nkL;
  bnd = bnd > NCACHE ? bnd : NCACHE;
  if (i0 >= bnd) return;

  __shared__ float tile[2][32][33];
  __shared__ unsigned long long keyL[8][32];
  const float* A = in + ((size_t)k << 16);
  float* Bp = out + ((size_t)k << 16);

  // preload j0 = 0 into buf 0
#pragma unroll
  for (int r = 0; r < 32; r += 8) {
    float x = A[(size_t)(ty + r) * NN + (i0 + tx)];
    tile[0][ty + r][tx] = isfinite(x) ? x : 1e6f;
  }
  __syncthreads();

  unsigned long long best = ~0ull;
  int buf = 0;
#pragma unroll 1
  for (int j0 = 0; j0 < NN; j0 += 32) {
    // store + row-min accumulate from tile[buf]
#pragma unroll
    for (int r = 0; r < 32; r += 8) {
      Bp[(size_t)(i0 + ty + r) * NN + (j0 + tx)] = tile[buf][tx][ty + r];
      const float v = tile[buf][ty + r][tx];  // Pt[i0+tx][j0+ty+r]
      const unsigned long long key =
          ((unsigned long long)f2o(v) << 32) | (unsigned)(j0 + ty + r);
      if (key < best) best = key;
    }
    // prefetch next column-tile into the other buffer
    if (j0 + 32 < NN) {
#pragma unroll
      for (int r = 0; r < 32; r += 8) {
        float x = A[(size_t)(j0 + 32 + ty + r) * NN + (i0 + tx)];
        tile[buf ^ 1][ty + r][tx] = isfinite(x) ? x : 1e6f;
      }
    }
    __syncthreads();  // single barrier: buf stores done, buf^1 loads done
    buf ^= 1;
  }

  keyL[ty][tx] = best;
  __syncthreads();
  if (ty == 0) {
    unsigned long long b = keyL[0][tx];
#pragma unroll
    for (int s = 1; s < 8; ++s) {
      const unsigned long long c = keyL[s][tx];
      if (c < b) b = c;
    }
    rmk[k * NN + i0 + tx] = b;
  }
}

// ---------------------------------------------------------------------------
// Legacy transpose (modes 0/1 fallback; no rmk side-channel).
// ---------------------------------------------------------------------------
__global__ __launch_bounds__(256)
void transpose_kernel(const float* __restrict__ in, float* __restrict__ out,
                      const int* __restrict__ nk) {
  const int k = blockIdx.z;
  const int i0 = blockIdx.x * 32;
  int bnd = nk[k];
  bnd = bnd > NCACHE ? bnd : NCACHE;
  if (i0 >= bnd) return;
  __shared__ float tile[32][33];
  const float* A = in + ((size_t)k << 16);
  float* Bp = out + ((size_t)k << 16);
  const int tx = threadIdx.x, ty = threadIdx.y;
  const int j0 = blockIdx.y * 32;
#pragma unroll
  for (int r = 0; r < 32; r += 8) {
    float x = A[(size_t)(j0 + ty + r) * NN + (i0 + tx)];
    tile[ty + r][tx] = isfinite(x) ? x : 1e6f;
  }
  __syncthreads();
#pragma unroll
  for (int r = 0; r < 32; r += 8) {
    Bp[(size_t)(i0 + ty + r) * NN + (j0 + tx)] = tile[tx][ty + r];
  }
}

// ---------------------------------------------------------------------------
// DPP wave64 u32 min (VALU-rate).
// ---------------------------------------------------------------------------
template <int CTRL>
__device__ __forceinline__ unsigned dpp_min_step(unsigned x) {
  unsigned y = (unsigned)__builtin_amdgcn_update_dpp((int)x, (int)x, CTRL, 0xF, 0xF, false);
  return y < x ? y : x;
}
__device__ __forceinline__ unsigned wave_min_u32(unsigned x) {
  x = dpp_min_step<0xB1>(x);   // quad_perm [1,0,3,2]
  x = dpp_min_step<0x4E>(x);   // quad_perm [2,3,0,1]
  x = dpp_min_step<0x141>(x);  // row_half_mirror
  x = dpp_min_step<0x140>(x);  // row_mirror
  x = dpp_min_step<0x142>(x);  // row_bcast15
  x = dpp_min_step<0x143>(x);  // row_bcast31
  return (unsigned)__builtin_amdgcn_readlane((int)x, 63);
}
__device__ __forceinline__ int sel4(const int a[4], int s) {
  return (s == 0) ? a[0] : (s == 1) ? a[1] : (s == 2) ? a[2] : a[3];
}
__device__ __forceinline__ void set4(int a[4], int s, int v) {
  if (s == 0) a[0] = v; else if (s == 1) a[1] = v;
  else if (s == 2) a[2] = v; else a[3] = v;
}
__device__ __forceinline__ void setf4(float a[4], int s, float v) {
  if (s == 0) a[0] = v; else if (s == 1) a[1] = v;
  else if (s == 2) a[2] = v; else a[3] = v;
}

// ---------------------------------------------------------------------------
// One wave64 per batch. Lane L owns cols 4L..4L+3 (v, shortest, pathrow, SC,
// row4col) and rows 4L..4L+3 (u, SR, col4row) in registers.
// mode 2: greedy init from packed rmk (u64 min|arg); parallel conflict
//         resolution (LDS atomicMin == serial first-come-lowest-row);
//         n_k read from nk[] (written by transpose_rowmin — R10 lesson).
// mode 1: R4-style in-lap greedy scan.  mode 0: strided direct.
// Phase 2: JV shortest augmenting path, exact reference float op order,
//          barrier-free (sh gathered via shuffles, not LDS) — R7: -41us.
// NOTE (R2): v must stay 0 in phase-1 duals (bit-exact slack requirement).
// NOTE (R5): NCACHE=61; 77 regressed. Fill is 8-deep pipelined (R6).
// Floor arithmetic (R10): slowest batch ~1350 Dijkstra steps x ~240cy
// (120cy LDS load + ~120cy dependent min/ballot chain) ~= 135us @2.4GHz;
// measured 129-133us => at the serial-latency floor for this algorithm.
// ---------------------------------------------------------------------------
__global__ __launch_bounds__(64)
void lap_kernel(const float* __restrict__ costs, const void* __restrict__ pm,
                const int* __restrict__ flag, const int* __restrict__ nkArr,
                const unsigned long long* __restrict__ rmk,
                const float* __restrict__ Pt, int* __restrict__ out, int mode) {
  const int k = blockIdx.x;
  const int lane = threadIdx.x;

  __shared__ __align__(16) float rowCache[NCACHE][NN];
  __shared__ int freeRowsL[NN];
  __shared__ int winnerL[NN];

  const float* PtK = Pt + ((size_t)k << 16);
  const float* costK = costs + ((size_t)k << 16);

  int n_k;
  if (mode >= 1) {
    n_k = nkArr[k];
  } else {
    const int fl = flag[0];
    int cnt4 = 0;
    if (fl == 1) {
      const int* p = ((const int*)pm) + k * NN;
#pragma unroll
      for (int q = 0; q < 4; ++q) cnt4 += (p[lane * 4 + q] != 0);
    } else if (fl == 2) {
      const float* p = ((const float*)pm) + k * NN;
#pragma unroll
      for (int q = 0; q < 4; ++q) cnt4 += (p[lane * 4 + q] != 0.0f);
    } else {
      const unsigned char* p = ((const unsigned char*)pm) + k * NN;
#pragma unroll
      for (int q = 0; q < 4; ++q) cnt4 += (p[lane * 4 + q] != 0);
    }
#pragma unroll
    for (int off = 32; off > 0; off >>= 1) cnt4 += __shfl_down(cnt4, off);
    n_k = __shfl(cnt4, 0);
  }

  float vv[4] = {0.f, 0.f, 0.f, 0.f};
  float uu[4] = {0.f, 0.f, 0.f, 0.f};
  int r4c[4] = {-1, -1, -1, -1};   // row4col, col-indexed
  int c4r[4] = {-1, -1, -1, -1};   // col4row, row-indexed
  int ja[4] = {-1, -1, -1, -1};    // greedy argmin per owned row
  int nfree = 0;                    // wave-uniform

  if (mode == 2) {
    // ---- fill LDS row cache, 8-deep software pipeline (R5 post-mortem) ----
#pragma unroll 1
    for (int base = 0; base + 8 <= NCACHE; base += 8) {
      float4 b[8];
#pragma unroll
      for (int r = 0; r < 8; ++r)
        b[r] = *(const float4*)(PtK + (size_t)(base + r) * NN + lane * 4);
#pragma unroll
      for (int r = 0; r < 8; ++r)
        *(float4*)(&rowCache[base + r][lane * 4]) = b[r];
    }
    {
      const int base = (NCACHE / 8) * 8;
      float4 b[NCACHE - (NCACHE / 8) * 8];
#pragma unroll
      for (int r = 0; r < NCACHE - (NCACHE / 8) * 8; ++r)
        b[r] = *(const float4*)(PtK + (size_t)(base + r) * NN + lane * 4);
#pragma unroll
      for (int r = 0; r < NCACHE - (NCACHE / 8) * 8; ++r)
        *(float4*)(&rowCache[base + r][lane * 4]) = b[r];
    }

    // ---- phase 1: greedy init from packed row minima ----
    const unsigned long long* rk = rmk + k * NN + lane * 4;
    unsigned long long kk[4];
#pragma unroll
    for (int q = 0; q < 4; ++q) kk[q] = rk[q];
#pragma unroll
    for (int q = 0; q < 4; ++q) {
      uu[q] = o2f((unsigned)(kk[q] >> 32));
      ja[q] = (int)(unsigned)(kk[q] & 0xFFFFFFFFu);
      if (lane * 4 + q >= n_k) uu[q] = 0.f;
    }

    // parallel conflict resolution: column winner = lowest claiming row
    // (identical to serial first-come walk in ascending row order).
    for (int t = lane; t < NN; t += 64) winnerL[t] = 0x7FFFFFFF;
    __syncthreads();
#pragma unroll
    for (int q = 0; q < 4; ++q) {
      const int row = lane * 4 + q;
      if (row < n_k) atomicMin(&winnerL[ja[q]], row);
    }
    __syncthreads();
#pragma unroll
    for (int s = 0; s < 4; ++s) {
      const int w = winnerL[lane * 4 + s];
      r4c[s] = (w == 0x7FFFFFFF) ? -1 : w;
    }
    unsigned fm = 0;
#pragma unroll
    for (int q = 0; q < 4; ++q) {
      const int row = lane * 4 + q;
      const bool valid = row < n_k;
      const bool won = valid && (winnerL[ja[q]] == row);
      c4r[q] = won ? ja[q] : -1;
      if (valid && !won) fm |= (1u << q);
    }
    // compact free rows ascending (row = 4*lane+q, lane-major == ascending)
    const int cnt = __popc(fm);
    int x = cnt;
#pragma unroll
    for (int off = 1; off < 64; off <<= 1) {
      const int y = __shfl_up(x, off);
      if (lane >= off) x += y;
    }
    nfree = __shfl(x, 63);
    int pos = x - cnt;
#pragma unroll
    for (int q = 0; q < 4; ++q) {
      if ((fm >> q) & 1u) { freeRowsL[pos] = lane * 4 + q; ++pos; }
    }
    __syncthreads();  // fill ds_writes + freeRowsL visible before phase 2
  } else {
    // ---- legacy fill (mode 1 / mode 0) ----
    if (mode >= 1) {
      const float4* s4 = (const float4*)PtK;
      float4* c4 = (float4*)rowCache;
      for (int t = lane; t < NCACHE * (NN / 4); t += 64) c4[t] = s4[t];
    } else {
      for (int e = lane; e < NCACHE * NN; e += 64) {
        const int i = e >> 8, j = e & 255;
        float x = costK[(size_t)j * NN + i];
        rowCache[i][j] = isfinite(x) ? x : 1e6f;
      }
    }
    __syncthreads();
    // ---- in-lap greedy scan (R4 behavior) ----
    float4 carry = {0.f, 0.f, 0.f, 0.f};
    for (int r = 0; r < n_k; ++r) {
      float cc[4];
      if (r < NCACHE) {
        const float4 rv = *(const float4*)(&rowCache[r][lane * 4]);
        cc[0] = rv.x; cc[1] = rv.y; cc[2] = rv.z; cc[3] = rv.w;
      } else if (mode >= 1) {
        cc[0] = carry.x; cc[1] = carry.y; cc[2] = carry.z; cc[3] = carry.w;
      } else {
#pragma unroll
        for (int q = 0; q < 4; ++q) {
          float x = costK[(size_t)(lane * 4 + q) * NN + r];
          cc[q] = isfinite(x) ? x : 1e6f;
        }
      }
      if (mode >= 1 && r + 1 >= NCACHE && r + 1 < n_k)
        carry = *(const float4*)(PtK + (size_t)(r + 1) * NN + lane * 4);

      unsigned lbv = 0xFFFFFFFFu;
      int lbq = 0;
#pragma unroll
      for (int q = 0; q < 4; ++q) {
        const unsigned m = f2o(cc[q]);
        if (m < lbv) { lbv = m; lbq = q; }
      }
      const unsigned gv = wave_min_u32(lbv);
      const unsigned long long cmask = __ballot(lbv == gv);
      const int owner = __ffsll((unsigned long long)cmask) - 1;
      const int js = (owner << 2) + __builtin_amdgcn_readlane(lbq, owner);
      if (lane == (r >> 2)) setf4(uu, r & 3, o2f(gv));
      const int occ = __builtin_amdgcn_readlane(sel4(r4c, js & 3), owner);
      if (occ < 0) {
        if (lane == owner) set4(r4c, js & 3, r);
        if (lane == (r >> 2)) set4(c4r, r & 3, js);
      } else {
        if (lane == 0) freeRowsL[nfree] = r;
        nfree++;
      }
    }
    __syncthreads();  // freeRowsL visible
  }

  // ---- phase 2: shortest augmenting path (barrier-free, registers+shfl) ----
  for (int t = 0; t < nfree; ++t) {
    const int cur = freeRowsL[t];
    float sh[4] = {LAP_INF, LAP_INF, LAP_INF, LAP_INF};
    int pr[4] = {-1, -1, -1, -1};
    unsigned scm = 0;  // SC bits, this lane's 4 cols
    unsigned srm = 0;  // SR bits, this lane's 4 rows
    float minval = 0.f;
    int i = cur, sink = -1;

    while (sink < 0) {
      const int islot = i & 3, iowner = i >> 2;
      if (lane == iowner) srm |= (1u << islot);
      const float su = (islot == 0) ? uu[0] : (islot == 1) ? uu[1]
                     : (islot == 2) ? uu[2] : uu[3];
      const float ui = __int_as_float(
          __builtin_amdgcn_readlane(__float_as_int(su), iowner));

      float cc[4];
      if (i < NCACHE) {
        const float4 rv = *(const float4*)(&rowCache[i][lane * 4]);
        cc[0] = rv.x; cc[1] = rv.y; cc[2] = rv.z; cc[3] = rv.w;
      } else if (mode >= 1) {
        const float4 rv = *(const float4*)(PtK + (size_t)i * NN + lane * 4);
        cc[0] = rv.x; cc[1] = rv.y; cc[2] = rv.z; cc[3] = rv.w;
      } else {
#pragma unroll
        for (int q = 0; q < 4; ++q) {
          float x = costK[(size_t)(lane * 4 + q) * NN + i];
          cc[q] = isfinite(x) ? x : 1e6f;
        }
      }

      unsigned mq[4];
#pragma unroll
      for (int q = 0; q < 4; ++q) {
        // exact reference order: ((minval + cost) - u[i]) - v[j]
        float r = minval + cc[q];
        r = r - ui;
        r = r - vv[q];
        const bool sc = (scm >> q) & 1u;
        if (!sc && r < sh[q]) { sh[q] = r; pr[q] = i; }
        mq[q] = sc ? 0xFFFFFFFFu : f2o(sh[q]);
      }
      // tree-structured lane-local argmin; strict < keeps first index.
      unsigned ma = mq[0]; int qa = 0;
      if (mq[1] < ma) { ma = mq[1]; qa = 1; }
      unsigned mc = mq[2]; int qc = 2;
      if (mq[3] < mc) { mc = mq[3]; qc = 3; }
      unsigned lbv = ma; int lbq = qa;
      if (mc < ma) { lbv = mc; lbq = qc; }

      // Pack (candidate next-row, q) pre-reduce; one readlane post-reduce.
      const int cand = sel4(r4c, lbq);
      const unsigned pack = (unsigned)lbq | ((unsigned)(cand + 1) << 2);

      const unsigned gv = wave_min_u32(lbv);
      minval = o2f(gv);
      const unsigned long long cmask = __ballot(lbv == gv);
      const int owner = __ffsll((unsigned long long)cmask) - 1;
      const unsigned pk = (unsigned)__builtin_amdgcn_readlane((int)pack, owner);
      const int js = (owner << 2) + (int)(pk & 3u);
      if (lane == owner) scm |= (1u << lbq);
      const int nxt = (int)(pk >> 2) - 1;
      if (nxt < 0) sink = js; else i = nxt;
    }

    // ---- dual updates (Crouse 2016): gather shortest[c4r[q]] via shfl ----
    float gv4[4];
#pragma unroll
    for (int q = 0; q < 4; ++q) {
      const int tgt = c4r[q] >= 0 ? c4r[q] : 0;  // clamp; unused when invalid
      const int srcLane = tgt >> 2, slot = tgt & 3;
      const float g0 = __shfl(sh[0], srcLane);
      const float g1 = __shfl(sh[1], srcLane);
      const float g2 = __shfl(sh[2], srcLane);
      const float g3 = __shfl(sh[3], srcLane);
      gv4[q] = (slot == 0) ? g0 : (slot == 1) ? g1 : (slot == 2) ? g2 : g3;
    }
#pragma unroll
    for (int q = 0; q < 4; ++q) {
      if ((srm >> q) & 1u) {
        const int row = lane * 4 + q;
        if (row == cur) uu[q] = uu[q] + minval;
        else uu[q] = uu[q] + (minval - gv4[q]);
      }
      if ((scm >> q) & 1u) vv[q] = vv[q] - (minval - sh[q]);
    }

    // ---- augment along alternating path: pure registers ----
    int j = sink;
    bool done = false;
    while (!done) {
      const int pi = __builtin_amdgcn_readlane(sel4(pr, j & 3), j >> 2);
      if (lane == (j >> 2)) set4(r4c, j & 3, pi);
      const int jn = __builtin_amdgcn_readlane(sel4(c4r, pi & 3), pi >> 2);
      if (lane == (pi >> 2)) set4(c4r, pi & 3, j);
      done = (pi == cur);
      j = jn;
    }
  }

  // ---- output: valid rows get col4row; padded rows get unused cols asc ----
  int* outK = out + k * NN;
#pragma unroll
  for (int q = 0; q < 4; ++q) {
    const int row = lane * 4 + q;
    if (row < n_k) outK[row] = c4r[q];
  }
  // column j unused <=> r4c[j&3] < 0 on lane j>>2 (only rows < n_k match).
  unsigned um = 0;
#pragma unroll
  for (int s = 0; s < 4; ++s)
    if (r4c[s] < 0) um |= (1u << s);
  const int uc = __popc(um);
  int ux = uc;
#pragma unroll
  for (int off = 1; off < 64; off <<= 1) {
    const int uy = __shfl_up(ux, off);
    if (lane >= off) ux += uy;
  }
  int upos = ux - uc;
#pragma unroll
  for (int s = 0; s < 4; ++s) {
    if ((um >> s) & 1u) { outK[n_k + upos] = lane * 4 + s; ++upos; }
  }
}

extern "C" void kernel_launch(void* const* d_in, const int* in_sizes, int n_in,
                              void* d_out, int out_size, void* d_ws, size_t ws_size,
                              hipStream_t stream) {
  const float* costs = (const float*)d_in[0];
  const void* pm = d_in[1];
  int* out = (int*)d_out;

  int* flag = (int*)d_ws;
  int* nk = (int*)((char*)d_ws + WS_NK_OFF);
  const size_t ptBytes = (size_t)NB * NN * NN * sizeof(float);

  int mode;
  unsigned long long* rmk; float* Pt;
  if (ws_size >= WS_PT_OFF_FULL + ptBytes) {
    mode = 2;
    rmk = (unsigned long long*)((char*)d_ws + WS_RMK_OFF);
    Pt = (float*)((char*)d_ws + WS_PT_OFF_FULL);
  } else if (ws_size >= WS_PT_OFF_R4 + ptBytes) {
    mode = 1;
    rmk = (unsigned long long*)d_ws;
    Pt = (float*)((char*)d_ws + WS_PT_OFF_R4);
  } else {
    mode = 0;
    rmk = (unsigned long long*)d_ws;
    Pt = (float*)costs;  // unused
  }

  detect_kernel<<<1, 1024, 0, stream>>>((const unsigned int*)pm, flag);
  if (mode == 2) {
    dim3 g(8, 1, NB), b(32, 8);
    transpose_rowmin_kernel<<<g, b, 0, stream>>>(costs, Pt, pm, flag, nk, rmk);
  } else if (mode == 1) {
    nk_kernel<<<NB, 64, 0, stream>>>(pm, flag, nk);
    dim3 g(8, 8, NB), b(32, 8);
    transpose_kernel<<<g, b, 0, stream>>>(costs, Pt, nk);
  }
  lap_kernel<<<NB, 64, 0, stream>>>(costs, pm, flag, nk, rmk, Pt, out, mode);
}